// Round 19
// baseline (14687.296 us; speedup 1.0000x reference)
//
#include <hip/hip_runtime.h>
#include <hip/hip_bf16.h>

#define T_   512
#define B_   128
#define E_   512
#define H_   512
#define G4_  2048
#define MEM_ 500
#define CTX_ 300
#define EC_  (E_ + CTX_)
#define SPIN_MAX 65536

typedef short sh8  __attribute__((ext_vector_type(8)));   // 8 bf16 (4 VGPR) MFMA frag
typedef float f32x4 __attribute__((ext_vector_type(4)));
typedef unsigned u32x4 __attribute__((ext_vector_type(4)));

struct ScanParams {
  const float* __restrict__ x;     // [B,T,E] fp32
  const short* __restrict__ xbf;   // [B,T,E] bf16 (ws precomputed; may be null)
  const int*   __restrict__ len;   // [B]
  const float* __restrict__ Wih0; const float* __restrict__ Whh0;
  const float* __restrict__ bih0; const float* __restrict__ bhh0;
  const float* __restrict__ Wih1; const float* __restrict__ Whh1;
  const float* __restrict__ bih1; const float* __restrict__ bhh1;
  const float* __restrict__ Mk0;  const float* __restrict__ Mk1;
  const float* __restrict__ Mf;   // [2,MEM,4H] fp32 (ws, precomputed)
  unsigned* __restrict__ hbU;     // [2par,2dir,B,H] u32: (bf16<<16)|epoch
  unsigned* __restrict__ aBU;     // [2dir,B,512]    u32: (bf16<<16)|epoch
  float* __restrict__ out;        // [B,2H] fp32
};

__device__ __forceinline__ float sigm_(float x) { return 1.f / (1.f + __expf(-x)); }
__device__ __forceinline__ float tanh_(float x) { return 1.f - 2.f / (__expf(2.f * x) + 1.f); }
__device__ __forceinline__ short f2bs(float f) {
  __hip_bfloat16 h = __float2bfloat16(f);
  short s; __builtin_memcpy(&s, &h, 2); return s;
}
__device__ __forceinline__ float bs2f(short s) {
  unsigned u = ((unsigned)(unsigned short)s) << 16;
  float f; __builtin_memcpy(&f, &u, 4); return f;
}

// ---- tagged-data batched load: per k (0..7) two dwordx4 at byte 128k, 128k+16
// (8 u32 = 8 tagged values = one MFMA fragment k-slice). Internal vmcnt(0)
// (r10 contract). The TAG VALIDATION of the loaded dwords IS the sync — no
// flags, no producer drain (single-dword stores are atomic value+epoch).
struct R16 { u32x4 v[16]; };
__device__ __forceinline__ void gld16p(R16& f, const unsigned* base) {
  asm volatile(
      "global_load_dwordx4 %0, %16, off sc1\n\t"
      "global_load_dwordx4 %1, %16, off offset:16 sc1\n\t"
      "global_load_dwordx4 %2, %16, off offset:128 sc1\n\t"
      "global_load_dwordx4 %3, %16, off offset:144 sc1\n\t"
      "global_load_dwordx4 %4, %16, off offset:256 sc1\n\t"
      "global_load_dwordx4 %5, %16, off offset:272 sc1\n\t"
      "global_load_dwordx4 %6, %16, off offset:384 sc1\n\t"
      "global_load_dwordx4 %7, %16, off offset:400 sc1\n\t"
      "global_load_dwordx4 %8, %16, off offset:512 sc1\n\t"
      "global_load_dwordx4 %9, %16, off offset:528 sc1\n\t"
      "global_load_dwordx4 %10, %16, off offset:640 sc1\n\t"
      "global_load_dwordx4 %11, %16, off offset:656 sc1\n\t"
      "global_load_dwordx4 %12, %16, off offset:768 sc1\n\t"
      "global_load_dwordx4 %13, %16, off offset:784 sc1\n\t"
      "global_load_dwordx4 %14, %16, off offset:896 sc1\n\t"
      "global_load_dwordx4 %15, %16, off offset:912 sc1\n\t"
      "s_waitcnt vmcnt(0)"
      : "=&v"(f.v[0]), "=&v"(f.v[1]), "=&v"(f.v[2]), "=&v"(f.v[3]),
        "=&v"(f.v[4]), "=&v"(f.v[5]), "=&v"(f.v[6]), "=&v"(f.v[7]),
        "=&v"(f.v[8]), "=&v"(f.v[9]), "=&v"(f.v[10]), "=&v"(f.v[11]),
        "=&v"(f.v[12]), "=&v"(f.v[13]), "=&v"(f.v[14]), "=&v"(f.v[15])
      : "v"(base)
      : "memory");
}

// validate tags (low16 == tag) and repack values (high16) into 8 sh8 frags
__device__ __forceinline__ unsigned vr8(const R16& r, unsigned tag, sh8* frag) {
  unsigned bad = 0;
  #pragma unroll
  for (int k = 0; k < 8; ++k) {
    u32x4 a = r.v[2 * k], b = r.v[2 * k + 1];
    #pragma unroll
    for (int j = 0; j < 4; ++j) {
      bad |= (a[j] & 0xffffu) ^ tag;
      bad |= (b[j] & 0xffffu) ^ tag;
    }
    u32x4 d;
    d[0] = (a[0] >> 16) | (a[1] & 0xffff0000u);
    d[1] = (a[2] >> 16) | (a[3] & 0xffff0000u);
    d[2] = (b[0] >> 16) | (b[1] & 0xffff0000u);
    d[3] = (b[2] >> 16) | (b[3] & 0xffff0000u);
    frag[k] = *reinterpret_cast<sh8*>(&d);
  }
  return bad;
}

// 4 tagged dword stores: rows r=0,1 on b01 (+0,+2048B), r=2,3 on b23 (no wait)
__device__ __forceinline__ void st4d(unsigned* b01, unsigned* b23,
                                     unsigned d0, unsigned d1, unsigned d2, unsigned d3) {
  asm volatile(
      "global_store_dword %4, %0, off sc1\n\t"
      "global_store_dword %4, %1, off offset:2048 sc1\n\t"
      "global_store_dword %5, %2, off sc1\n\t"
      "global_store_dword %5, %3, off offset:2048 sc1"
      :: "v"(d0), "v"(d1), "v"(d2), "v"(d3), "v"(b01), "v"(b23) : "memory");
}

// 8 tagged dword stores: (ct2=0: +0, ct2=1: +16B) x rows 0..3 split over b01/b23
__device__ __forceinline__ void st8d(unsigned* b01, unsigned* b23, const unsigned* d) {
  asm volatile(
      "global_store_dword %8, %0, off sc1\n\t"
      "global_store_dword %8, %1, off offset:2048 sc1\n\t"
      "global_store_dword %9, %2, off sc1\n\t"
      "global_store_dword %9, %3, off offset:2048 sc1\n\t"
      "global_store_dword %8, %4, off offset:16 sc1\n\t"
      "global_store_dword %8, %5, off offset:2064 sc1\n\t"
      "global_store_dword %9, %6, off offset:16 sc1\n\t"
      "global_store_dword %9, %7, off offset:2064 sc1"
      :: "v"(d[0]), "v"(d[1]), "v"(d[2]), "v"(d[3]),
         "v"(d[4]), "v"(d[5]), "v"(d[6]), "v"(d[7]), "v"(b01), "v"(b23) : "memory");
}

// x fp32 -> bf16, same [B,T,E] layout
__global__ __launch_bounds__(256) void xcvt_kernel(const float* __restrict__ x,
                                                   short* __restrict__ xbf) {
  const size_t i = ((size_t)blockIdx.x * 256 + threadIdx.x) * 8;
  f32x4 a = *reinterpret_cast<const f32x4*>(x + i);
  f32x4 b = *reinterpret_cast<const f32x4*>(x + i + 4);
  sh8 v;
  #pragma unroll
  for (int j = 0; j < 4; ++j) { v[j] = f2bs(a[j]); v[4 + j] = f2bs(b[j]); }
  *reinterpret_cast<sh8*>(xbf + i) = v;
}

// Mfused[d][m][j] = sum_c Mv_d[c][m] * Wih_d[j][E+c]   (fp32)
__global__ __launch_bounds__(256) void mfused_kernel(
    const float* __restrict__ WihF, const float* __restrict__ WihB,
    const float* __restrict__ MvF,  const float* __restrict__ MvB,
    float* __restrict__ Mf) {
  const int d  = blockIdx.x >> 7;
  const int j0 = (blockIdx.x & 127) * 16;
  const float* __restrict__ Wih = d ? WihB : WihF;
  const float* __restrict__ Mv  = d ? MvB  : MvF;
  __shared__ float Wl[16][CTX_ + 1];
  for (int i = threadIdx.x; i < 16 * CTX_; i += 256) {
    int r = i / CTX_, cc = i - r * CTX_;
    Wl[r][cc] = Wih[(size_t)(j0 + r) * EC_ + E_ + cc];
  }
  __syncthreads();
  const int jj = threadIdx.x & 15;
  for (int m = threadIdx.x >> 4; m < MEM_; m += 16) {
    float acc = 0.f;
    for (int cc = 0; cc < CTX_; ++cc)
      acc = fmaf(Mv[cc * MEM_ + m], Wl[jj][cc], acc);
    Mf[(size_t)d * MEM_ * G4_ + (size_t)m * G4_ + j0 + jj] = acc;
  }
}

__global__ __launch_bounds__(512, 1) void scan_kernel(ScanParams p) {
  const int dir  = blockIdx.x >> 6;   // 0 fwd, 1 bwd (64 WGs each)
  const int w    = blockIdx.x & 63;   // WG within dir: owns cells 8w..8w+7
  const int tid  = threadIdx.x;
  const int wv   = tid >> 6;          // wave 0..7 == batch row-tile owner
  const int lane = tid & 63;

  __shared__ __align__(16) short WgL[32 * 2 * 64 * 8];  // gate W own-cols 64 KB
  __shared__ __align__(16) short MkL[16 * 64 * 8];      // attn Mk coltile 16 KB
  __shared__ __align__(16) short MfL[16 * 2 * 64 * 8];  // ctx Mf own-cols 32 KB
  __shared__ int LvL[B_];

  const float* __restrict__ Wihd = dir ? p.Wih1 : p.Wih0;
  const float* __restrict__ Whhd = dir ? p.Whh1 : p.Whh0;
  const float* __restrict__ bihd = dir ? p.bih1 : p.bih0;
  const float* __restrict__ bhhd = dir ? p.bhh1 : p.bhh0;
  const float* __restrict__ Mkd  = dir ? p.Mk1  : p.Mk0;
  const float* __restrict__ Mfd  = p.Mf + (size_t)dir * MEM_ * G4_;
  unsigned* __restrict__ aBU_d = p.aBU + (size_t)dir * B_ * 512;

  // balanced producers (r18): WG w produces coltile ct=w>>1 for row-half w&1
  const int  ct   = w >> 1;
  const bool prod = ((wv >> 2) == (w & 1));

  // ---- one-time LDS preload (fragment order) ----
  for (int i = tid; i < 32 * 2 * 64; i += 512) {    // gates: [ks][ct2][lane]
    const int ks = i >> 7, r2 = i & 127, ct2 = r2 >> 6, l2 = r2 & 63;
    const int col = l2 & 15, kg = l2 >> 4;
    const int k0 = ks * 32 + kg * 8;
    const int gc = (col & 3) * H_ + 8 * w + 4 * ct2 + (col >> 2);
    const float* src = (k0 < E_) ? (Wihd + (size_t)gc * EC_ + k0)
                                 : (Whhd + (size_t)gc * H_ + (k0 - E_));
    sh8 v;
    #pragma unroll
    for (int j = 0; j < 8; ++j) v[j] = f2bs(src[j]);
    *reinterpret_cast<sh8*>(&WgL[i * 8]) = v;
  }
  for (int i = tid; i < 16 * 64; i += 512) {        // Mk: [ks][lane]
    const int ks = i >> 6, l2 = i & 63;
    const int col = l2 & 15, kg = l2 >> 4;
    const int k0 = ks * 32 + kg * 8;
    const int mr = 16 * ct + col;
    sh8 v;
    #pragma unroll
    for (int j = 0; j < 8; ++j)
      v[j] = (mr < MEM_) ? f2bs(Mkd[(size_t)mr * H_ + k0 + j]) : (short)0;
    *reinterpret_cast<sh8*>(&MkL[i * 8]) = v;
  }
  for (int i = tid; i < 16 * 2 * 64; i += 512) {    // Mf: [ks][ct2][lane]
    const int ks = i >> 7, r2 = i & 127, ct2 = r2 >> 6, l2 = r2 & 63;
    const int col = l2 & 15, kg = l2 >> 4;
    const int gc = (col & 3) * H_ + 8 * w + 4 * ct2 + (col >> 2);
    const int m0 = ks * 32 + kg * 8;
    sh8 v;
    #pragma unroll
    for (int j = 0; j < 8; ++j)
      v[j] = (m0 + j < MEM_) ? f2bs(Mfd[(size_t)(m0 + j) * G4_ + gc]) : (short)0;
    *reinterpret_cast<sh8*>(&MfL[i * 8]) = v;
  }
  if (tid < B_) LvL[tid] = p.len[tid];

  // per-lane cell mapping
  const int cc  = lane & 15;
  const int q   = cc & 3;
  const int uu  = cc >> 2;
  const int g2  = lane >> 4;
  const int kg8 = g2 * 8;
  const int arow = lane & 15;
  float biasl[2];
  #pragma unroll
  for (int ct2 = 0; ct2 < 2; ++ct2) {
    const int gc = q * H_ + 8 * w + 4 * ct2 + uu;
    biasl[ct2] = bihd[gc] + bhhd[gc];
  }

  float creg[2][4] = {{0.f,0.f,0.f,0.f},{0.f,0.f,0.f,0.f}};
  __syncthreads();                     // LDS + LvL ready (only barrier in kernel)

  const int mylen = LvL[16 * wv + arow];

  // poll-load-validate-repack: the tag check IS the synchronization
  auto poll16 = [&](const unsigned* base, unsigned tag, sh8* frag) {
    R16 r;
    int n = 0;
    for (;;) {
      gld16p(r, base);
      unsigned bad = vr8(r, tag, frag);
      if (__all((int)(bad == 0)) || n >= SPIN_MAX) break;
      __builtin_amdgcn_s_sleep(1); ++n;
    }
  };

  // gate x-half MFMA (xbf / x only; no cross-WG dependence)
  auto xhalf = [&](int t, f32x4* acc) {
    if (p.xbf) {
      const short* xb = p.xbf + ((size_t)(16 * wv + arow) * T_ + t) * E_ + kg8;
      for (int ks = 0; ks < 16; ++ks) {
        sh8 af = *reinterpret_cast<const sh8*>(xb + ks * 32);
        acc[0] = __builtin_amdgcn_mfma_f32_16x16x32_bf16(
            af, *reinterpret_cast<const sh8*>(&WgL[((ks * 2 + 0) * 64 + lane) * 8]), acc[0], 0, 0, 0);
        acc[1] = __builtin_amdgcn_mfma_f32_16x16x32_bf16(
            af, *reinterpret_cast<const sh8*>(&WgL[((ks * 2 + 1) * 64 + lane) * 8]), acc[1], 0, 0, 0);
      }
    } else {
      const float* xp0 = p.x + ((size_t)(16 * wv + arow) * T_ + t) * E_ + kg8;
      for (int ks = 0; ks < 16; ++ks) {
        f32x4 v0 = *reinterpret_cast<const f32x4*>(xp0 + ks * 32);
        f32x4 v1 = *reinterpret_cast<const f32x4*>(xp0 + ks * 32 + 4);
        sh8 af;
        #pragma unroll
        for (int j = 0; j < 4; ++j) { af[j] = f2bs(v0[j]); af[4 + j] = f2bs(v1[j]); }
        acc[0] = __builtin_amdgcn_mfma_f32_16x16x32_bf16(
            af, *reinterpret_cast<const sh8*>(&WgL[((ks * 2 + 0) * 64 + lane) * 8]), acc[0], 0, 0, 0);
        acc[1] = __builtin_amdgcn_mfma_f32_16x16x32_bf16(
            af, *reinterpret_cast<const sh8*>(&WgL[((ks * 2 + 1) * 64 + lane) * 8]), acc[1], 0, 0, 0);
      }
    }
  };

  f32x4 accX[2] = {(f32x4){0,0,0,0}, (f32x4){0,0,0,0}};
  xhalf(dir ? T_ - 1 : 0, accX);                    // prologue: x-half for step 0

  for (int s = 0; s < T_; ++s) {
    const int t   = dir ? (T_ - 1 - s) : s;
    const int cur = s & 1, prv = cur ^ 1;
    const unsigned* __restrict__ hb_prevU = p.hbU + ((size_t)(prv * 2 + dir)) * B_ * H_;
    unsigned*       __restrict__ hb_curU  = p.hbU + ((size_t)(cur * 2 + dir)) * B_ * H_;

    const unsigned tagH = (unsigned)s;        // h written at step s-1 carries s
    const unsigned tagW = (unsigned)(s + 1);  // everything we write this step

    f32x4 accG[2] = { accX[0], accX[1] };     // x-half (prefetched)

    // ===== A: tagged h read — poll directly on data (1-RT handoff)
    sh8 fHf[16];
    {
      const unsigned* hbase = hb_prevU + (size_t)(16 * wv + arow) * 512 + kg8;
      poll16(hbase,       tagH, &fHf[0]);
      poll16(hbase + 256, tagH, &fHf[8]);
    }

    // ===== B: balanced producers: attn logits -> exp -> tagged aB (no drain)
    if (prod) {
      f32x4 accA = (f32x4){0, 0, 0, 0};
      const sh8 z8 = (sh8){0,0,0,0,0,0,0,0};
      const bool keep = !dir || ((t + 1) < mylen);
      #pragma unroll
      for (int ks = 0; ks < 16; ++ks) {
        sh8 af = keep ? fHf[ks] : z8;
        accA = __builtin_amdgcn_mfma_f32_16x16x32_bf16(
            af, *reinterpret_cast<const sh8*>(&MkL[(ks * 64 + lane) * 8]), accA, 0, 0, 0);
      }
      const int m = 16 * ct + arow;
      unsigned d[4];
      #pragma unroll
      for (int r = 0; r < 4; ++r) {
        float e = (m < MEM_) ? __expf(accA[r]) : 0.f;
        d[r] = ((unsigned)(unsigned short)f2bs(e) << 16) | tagW;
      }
      unsigned* ab01 = aBU_d + (size_t)(16 * wv + 4 * g2) * 512 + m;
      st4d(ab01, ab01 + 1024, d[0], d[1], d[2], d[3]);
    }

    // ===== C: gate h-half MFMA (overlaps producers' stores landing)
    #pragma unroll
    for (int ks = 0; ks < 16; ++ks) {
      accG[0] = __builtin_amdgcn_mfma_f32_16x16x32_bf16(
          fHf[ks], *reinterpret_cast<const sh8*>(&WgL[(((16 + ks) * 2 + 0) * 64 + lane) * 8]), accG[0], 0, 0, 0);
      accG[1] = __builtin_amdgcn_mfma_f32_16x16x32_bf16(
          fHf[ks], *reinterpret_cast<const sh8*>(&WgL[(((16 + ks) * 2 + 1) * 64 + lane) * 8]), accG[1], 0, 0, 0);
    }

    // ===== F: next step's x-half prefetch fills the aB wait window
    accX[0] = (f32x4){0,0,0,0}; accX[1] = (f32x4){0,0,0,0};
    if (s + 1 < T_) xhalf(dir ? (T_ - 2 - s) : (s + 1), accX);

    // ===== D: tagged aB read — poll on data; ctx MFMA + softmax denom
    f32x4 accC[2] = {(f32x4){0,0,0,0}, (f32x4){0,0,0,0}};
    float inv4[4] = {0.f, 0.f, 0.f, 0.f};
    if (s > 0) {
      float rs = 0.f;
      const unsigned* cb = aBU_d + (size_t)(16 * wv + arow) * 512 + kg8;
      #pragma unroll
      for (int c = 0; c < 2; ++c) {
        sh8 fCf[8];
        poll16(cb + 256 * c, tagW, fCf);
        #pragma unroll
        for (int k = 0; k < 8; ++k) {
          const int ks = 8 * c + k;
          accC[0] = __builtin_amdgcn_mfma_f32_16x16x32_bf16(
              fCf[k], *reinterpret_cast<const sh8*>(&MfL[((ks * 2 + 0) * 64 + lane) * 8]), accC[0], 0, 0, 0);
          accC[1] = __builtin_amdgcn_mfma_f32_16x16x32_bf16(
              fCf[k], *reinterpret_cast<const sh8*>(&MfL[((ks * 2 + 1) * 64 + lane) * 8]), accC[1], 0, 0, 0);
          #pragma unroll
          for (int j = 0; j < 8; ++j) rs += bs2f(fCf[k][j]);
        }
      }
      rs += __shfl_xor(rs, 16);
      rs += __shfl_xor(rs, 32);                     // lane holds rowsum(16wv+arow)
      #pragma unroll
      for (int r = 0; r < 4; ++r)
        inv4[r] = 1.f / __shfl(rs, 4 * g2 + r);
    }

    // ===== E: cell update + tagged h stores (no drain, no flag)
    unsigned hsd[8]; float hvv[2][4];
    #pragma unroll
    for (int ct2 = 0; ct2 < 2; ++ct2) {
      float g4[4];
      #pragma unroll
      for (int r = 0; r < 4; ++r) {
        float v = accG[ct2][r] + biasl[ct2];
        if (s > 0) v += accC[ct2][r] * inv4[r];
        g4[r] = v;
      }
      #pragma unroll
      for (int r = 0; r < 4; ++r) {
        const float x1 = __shfl_xor(g4[r], 1);
        const float x2 = __shfl_xor(g4[r], 2);
        const float x3 = __shfl_xor(g4[r], 3);
        const float iv = (q==0)?g4[r]:(q==1)?x1:(q==2)?x2:x3;
        const float fv = (q==0)?x1:(q==1)?g4[r]:(q==2)?x3:x2;
        const float gv = (q==0)?x2:(q==1)?x3:(q==2)?g4[r]:x1;
        const float ov = (q==0)?x3:(q==1)?x2:(q==2)?x1:g4[r];
        float cv = creg[ct2][r];
        cv = sigm_(fv) * cv + sigm_(iv) * tanh_(gv);
        const float hv = sigm_(ov) * tanh_(cv);
        creg[ct2][r] = cv;
        hvv[ct2][r] = hv;
        hsd[ct2 * 4 + r] = ((unsigned)(unsigned short)f2bs(hv) << 16) | tagW;
      }
    }
    if (q == 0) {
      const int b0 = 16 * wv + 4 * g2;
      const int unit0 = 8 * w + uu;
      unsigned* hb01 = hb_curU + (size_t)b0 * 512 + unit0;
      unsigned hord[8] = {hsd[0],hsd[1],hsd[2],hsd[3],hsd[4],hsd[5],hsd[6],hsd[7]};
      st8d(hb01, hb01 + 1024, hord);
      #pragma unroll
      for (int ct2 = 0; ct2 < 2; ++ct2) {
        #pragma unroll
        for (int r = 0; r < 4; ++r) {
          const int b = b0 + r;
          const int unit = unit0 + 4 * ct2;
          if (dir == 0) {
            if (t == LvL[b] - 1) p.out[b * (2 * H_) + 2 * unit] = hvv[ct2][r];
          } else {
            if (s == T_ - 1) p.out[b * (2 * H_) + 2 * unit + 1] = hvv[ct2][r];
          }
        }
      }
    }
    // no drain, no flag: consumers validate per-element epochs directly
  }
}

extern "C" void kernel_launch(void* const* d_in, const int* in_sizes, int n_in,
                              void* d_out, int out_size, void* d_ws, size_t ws_size,
                              hipStream_t stream) {
  (void)in_sizes; (void)n_in; (void)out_size;

  ScanParams p;
  p.x    = (const float*)d_in[0];
  p.len  = (const int*)  d_in[1];
  p.Wih0 = (const float*)d_in[2];
  p.Whh0 = (const float*)d_in[3];
  p.bih0 = (const float*)d_in[4];
  p.bhh0 = (const float*)d_in[5];
  p.Wih1 = (const float*)d_in[6];
  p.Whh1 = (const float*)d_in[7];
  p.bih1 = (const float*)d_in[8];
  p.bhh1 = (const float*)d_in[9];
  p.Mk0  = (const float*)d_in[10];
  const float* MvF = (const float*)d_in[11];
  p.Mk1  = (const float*)d_in[12];
  const float* MvB = (const float*)d_in[13];

  char* ws = (char*)d_ws;
  size_t off = 0;
  auto alloc = [&](size_t bytes) -> void* {
    void* ptr = ws + off; off += (bytes + 255) & ~(size_t)255; return ptr;
  };
  float*    Mf  = (float*)   alloc((size_t)2 * MEM_ * G4_ * 4);       // 8.19 MB
  unsigned* hbU = (unsigned*)alloc((size_t)2 * 2 * B_ * H_ * 4);      // 1 MB tagged h
  unsigned* aBU = (unsigned*)alloc((size_t)2 * B_ * 512 * 4);         // 512 KB tagged aB
  size_t xbf_off = off;
  short*    xbf = (short*)   alloc((size_t)B_ * T_ * E_ * 2);         // 67 MB
  const bool useXbf = (ws_size >= xbf_off + (size_t)B_ * T_ * E_ * 2);

  p.Mf = Mf; p.hbU = hbU; p.aBU = aBU;
  p.xbf = useXbf ? xbf : nullptr;
  p.out = (float*)d_out;

  // zero tagged state each call (hbU: tag0==epoch0 at s=0; aBU: kill replay tags)
  hipMemsetAsync(hbU, 0, (size_t)2 * 2 * B_ * H_ * 4 + (size_t)2 * B_ * 512 * 4, stream);

  if (useXbf) {
    const size_t n8 = (size_t)B_ * T_ * E_ / 8;
    xcvt_kernel<<<dim3((unsigned)(n8 / 256)), dim3(256), 0, stream>>>(p.x, xbf);
  }
  mfused_kernel<<<dim3(256), dim3(256), 0, stream>>>(
      (const float*)d_in[2], (const float*)d_in[6], MvF, MvB, Mf);

  void* args[] = { &p };
  hipLaunchCooperativeKernel((const void*)scan_kernel, dim3(128), dim3(512),
                             args, 0, stream);
}

// Round 20
// 9379.798 us; speedup vs baseline: 1.5658x; 1.5658x over previous
//
#include <hip/hip_runtime.h>
#include <hip/hip_bf16.h>

#define T_   512
#define B_   128
#define E_   512
#define H_   512
#define G4_  2048
#define MEM_ 500
#define CTX_ 300
#define EC_  (E_ + CTX_)
#define SPIN_MAX 65536

typedef short sh8  __attribute__((ext_vector_type(8)));   // 8 bf16 (4 VGPR) MFMA frag
typedef float f32x4 __attribute__((ext_vector_type(4)));

struct ScanParams {
  const float* __restrict__ x;     // [B,T,E] fp32
  const short* __restrict__ xbf;   // [B,T,E] bf16 (ws precomputed; may be null)
  const int*   __restrict__ len;   // [B]
  const float* __restrict__ Wih0; const float* __restrict__ Whh0;
  const float* __restrict__ bih0; const float* __restrict__ bhh0;
  const float* __restrict__ Wih1; const float* __restrict__ Whh1;
  const float* __restrict__ bih1; const float* __restrict__ bhh1;
  const float* __restrict__ Mk0;  const float* __restrict__ Mk1;
  const float* __restrict__ Mf;   // [2,MEM,4H] fp32 (ws, precomputed)
  short* __restrict__ hbf;        // [2par,2dir,B,H]  bf16 hidden
  short* __restrict__ aB;         // [2dir,B,512] bf16 exp-logits (single buffer)
  unsigned* __restrict__ bar;     // dense per-wave flag rows (zeroed per call)
  float* __restrict__ out;        // [B,2H] fp32
};

__device__ __forceinline__ float sigm_(float x) { return 1.f / (1.f + __expf(-x)); }
__device__ __forceinline__ float tanh_(float x) { return 1.f - 2.f / (__expf(2.f * x) + 1.f); }
__device__ __forceinline__ short f2bs(float f) {
  __hip_bfloat16 h = __float2bfloat16(f);
  short s; __builtin_memcpy(&s, &h, 2); return s;
}
__device__ __forceinline__ float bs2f(short s) {
  unsigned u = ((unsigned)(unsigned short)s) << 16;
  float f; __builtin_memcpy(&f, &u, 4); return f;
}

// ---- batched device-scope loads: 16x dwordx4 from one base, stride 64B ----
// CONTRACT: waits vmcnt(0) INSIDE the asm (r10 fix — no phantom outstanding
// ops skewing the compiler's waitcnt bookkeeping). Issue only AFTER the
// producer flag has been observed (strict order, r7 lesson).
struct F16 { sh8 v[16]; };
__device__ __forceinline__ void gld16(F16& f, const short* base) {
  asm volatile(
      "global_load_dwordx4 %0, %16, off sc1\n\t"
      "global_load_dwordx4 %1, %16, off offset:64 sc1\n\t"
      "global_load_dwordx4 %2, %16, off offset:128 sc1\n\t"
      "global_load_dwordx4 %3, %16, off offset:192 sc1\n\t"
      "global_load_dwordx4 %4, %16, off offset:256 sc1\n\t"
      "global_load_dwordx4 %5, %16, off offset:320 sc1\n\t"
      "global_load_dwordx4 %6, %16, off offset:384 sc1\n\t"
      "global_load_dwordx4 %7, %16, off offset:448 sc1\n\t"
      "global_load_dwordx4 %8, %16, off offset:512 sc1\n\t"
      "global_load_dwordx4 %9, %16, off offset:576 sc1\n\t"
      "global_load_dwordx4 %10, %16, off offset:640 sc1\n\t"
      "global_load_dwordx4 %11, %16, off offset:704 sc1\n\t"
      "global_load_dwordx4 %12, %16, off offset:768 sc1\n\t"
      "global_load_dwordx4 %13, %16, off offset:832 sc1\n\t"
      "global_load_dwordx4 %14, %16, off offset:896 sc1\n\t"
      "global_load_dwordx4 %15, %16, off offset:960 sc1\n\t"
      "s_waitcnt vmcnt(0)"
      : "=&v"(f.v[0]), "=&v"(f.v[1]), "=&v"(f.v[2]), "=&v"(f.v[3]),
        "=&v"(f.v[4]), "=&v"(f.v[5]), "=&v"(f.v[6]), "=&v"(f.v[7]),
        "=&v"(f.v[8]), "=&v"(f.v[9]), "=&v"(f.v[10]), "=&v"(f.v[11]),
        "=&v"(f.v[12]), "=&v"(f.v[13]), "=&v"(f.v[14]), "=&v"(f.v[15])
      : "v"(base)
      : "memory");
}

// 4 short stores (b-stride 1024B) + internal drain, device scope
__device__ __forceinline__ void st4s(short* base, unsigned d0, unsigned d1,
                                     unsigned d2, unsigned d3) {
  asm volatile(
      "global_store_short %4, %0, off sc1\n\t"
      "global_store_short %4, %1, off offset:1024 sc1\n\t"
      "global_store_short %4, %2, off offset:2048 sc1\n\t"
      "global_store_short %4, %3, off offset:3072 sc1\n\t"
      "s_waitcnt vmcnt(0)"
      :: "v"(d0), "v"(d1), "v"(d2), "v"(d3), "v"(base) : "memory");
}

// 8 short stores: rows +0..3 (1024B apart) at +0 and +8 bytes (no wait; caller
// drains before the flag set)
__device__ __forceinline__ void st8s(short* base, const unsigned* d) {
  asm volatile(
      "global_store_short %8, %0, off sc1\n\t"
      "global_store_short %8, %1, off offset:1024 sc1\n\t"
      "global_store_short %8, %2, off offset:2048 sc1\n\t"
      "global_store_short %8, %3, off offset:3072 sc1\n\t"
      "global_store_short %8, %4, off offset:8 sc1\n\t"
      "global_store_short %8, %5, off offset:1032 sc1\n\t"
      "global_store_short %8, %6, off offset:2056 sc1\n\t"
      "global_store_short %8, %7, off offset:3080 sc1"
      :: "v"(d[0]), "v"(d[1]), "v"(d[2]), "v"(d[3]),
         "v"(d[4]), "v"(d[5]), "v"(d[6]), "v"(d[7]), "v"(base) : "memory");
}

// ---- DENSE per-wave flag rows (epoch-monotonic, agent scope) ----
__device__ __forceinline__ bool hchk(const unsigned* hflW, unsigned ep, int lane) {
  unsigned v = __hip_atomic_load(&hflW[lane], __ATOMIC_RELAXED, __HIP_MEMORY_SCOPE_AGENT);
  return __all((int)(v >= ep));
}
__device__ __forceinline__ bool achk(const unsigned* aflW, unsigned ep, int lane) {
  unsigned v = __hip_atomic_load(&aflW[lane & 31], __ATOMIC_RELAXED, __HIP_MEMORY_SCOPE_AGENT);
  return __all((int)(v >= ep));
}
__device__ __forceinline__ void spin_h(const unsigned* hflW, unsigned ep, int lane) {
  int n = 0;
  while (!hchk(hflW, ep, lane) && n < SPIN_MAX) { __builtin_amdgcn_s_sleep(1); ++n; }
}
__device__ __forceinline__ void spin_a(const unsigned* aflW, unsigned ep, int lane) {
  int n = 0;
  while (!achk(aflW, ep, lane) && n < SPIN_MAX) { __builtin_amdgcn_s_sleep(1); ++n; }
}
__device__ __forceinline__ void fset(unsigned* slot, unsigned ep, int lane) {
  if (lane == 0)
    __hip_atomic_store(slot, ep, __ATOMIC_RELAXED, __HIP_MEMORY_SCOPE_AGENT);
}

// x fp32 -> bf16, same [B,T,E] layout
__global__ __launch_bounds__(256) void xcvt_kernel(const float* __restrict__ x,
                                                   short* __restrict__ xbf) {
  const size_t i = ((size_t)blockIdx.x * 256 + threadIdx.x) * 8;
  f32x4 a = *reinterpret_cast<const f32x4*>(x + i);
  f32x4 b = *reinterpret_cast<const f32x4*>(x + i + 4);
  sh8 v;
  #pragma unroll
  for (int j = 0; j < 4; ++j) { v[j] = f2bs(a[j]); v[4 + j] = f2bs(b[j]); }
  *reinterpret_cast<sh8*>(xbf + i) = v;
}

// Mfused[d][m][j] = sum_c Mv_d[c][m] * Wih_d[j][E+c]   (fp32)
__global__ __launch_bounds__(256) void mfused_kernel(
    const float* __restrict__ WihF, const float* __restrict__ WihB,
    const float* __restrict__ MvF,  const float* __restrict__ MvB,
    float* __restrict__ Mf) {
  const int d  = blockIdx.x >> 7;
  const int j0 = (blockIdx.x & 127) * 16;
  const float* __restrict__ Wih = d ? WihB : WihF;
  const float* __restrict__ Mv  = d ? MvB  : MvF;
  __shared__ float Wl[16][CTX_ + 1];
  for (int i = threadIdx.x; i < 16 * CTX_; i += 256) {
    int r = i / CTX_, cc = i - r * CTX_;
    Wl[r][cc] = Wih[(size_t)(j0 + r) * EC_ + E_ + cc];
  }
  __syncthreads();
  const int jj = threadIdx.x & 15;
  for (int m = threadIdx.x >> 4; m < MEM_; m += 16) {
    float acc = 0.f;
    for (int cc = 0; cc < CTX_; ++cc)
      acc = fmaf(Mv[cc * MEM_ + m], Wl[jj][cc], acc);
    Mf[(size_t)d * MEM_ * G4_ + (size_t)m * G4_ + j0 + jj] = acc;
  }
}

__global__ __launch_bounds__(512, 1) void scan_kernel(ScanParams p) {
  const int dir  = blockIdx.x >> 6;   // 0 fwd, 1 bwd (64 WGs each)
  const int w    = blockIdx.x & 63;   // WG within dir: owns cells 8w..8w+7
  const int tid  = threadIdx.x;
  const int wv   = tid >> 6;          // wave 0..7 == batch row-tile owner
  const int lane = tid & 63;

  // weights in MFMA B-fragment order -> linear per-lane ds_read_b128, no conflicts
  __shared__ __align__(16) short WgL[32 * 2 * 64 * 8];  // gate W own-cols [16][K=1024] 64 KB
  __shared__ __align__(16) short MkL[16 * 64 * 8];      // attn Mk coltile 16 KB
  __shared__ __align__(16) short MfL[16 * 2 * 64 * 8];  // ctx Mf own-cols 32 KB
  __shared__ int LvL[B_];

  const float* __restrict__ Wihd = dir ? p.Wih1 : p.Wih0;
  const float* __restrict__ Whhd = dir ? p.Whh1 : p.Whh0;
  const float* __restrict__ bihd = dir ? p.bih1 : p.bih0;
  const float* __restrict__ bhhd = dir ? p.bhh1 : p.bhh0;
  const float* __restrict__ Mkd  = dir ? p.Mk1  : p.Mk0;
  const float* __restrict__ Mfd  = p.Mf + (size_t)dir * MEM_ * G4_;
  short* __restrict__ aBd = p.aB + (size_t)dir * B_ * 512;

  // dense flag rows for THIS wave's row-slice
  unsigned* __restrict__ hflW = p.bar + (size_t)(dir * 8 + wv) * 64;
  unsigned* __restrict__ aflW = p.bar + 1024 + (size_t)(dir * 8 + wv) * 32;

  // BALANCED producers: every WG produces coltile ct = w>>1 for row-half
  // par = w&1, using its 4 waves with (wv>>2)==par (their own rows). Work is
  // symmetric across all WGs -> smaller slowest-of-128 straggler term.
  // Flag slot aflW[dir][wv][ct] is set by exactly one wave, as before.
  const int  ct   = w >> 1;
  const bool prod = ((wv >> 2) == (w & 1));

  // ---- one-time LDS preload (fragment order) ----
  for (int i = tid; i < 32 * 2 * 64; i += 512) {    // gates: [ks][ct2][lane]
    const int ks = i >> 7, r2 = i & 127, ct2 = r2 >> 6, l2 = r2 & 63;
    const int col = l2 & 15, kg = l2 >> 4;
    const int k0 = ks * 32 + kg * 8;
    const int gc = (col & 3) * H_ + 8 * w + 4 * ct2 + (col >> 2);
    const float* src = (k0 < E_) ? (Wihd + (size_t)gc * EC_ + k0)
                                 : (Whhd + (size_t)gc * H_ + (k0 - E_));
    sh8 v;
    #pragma unroll
    for (int j = 0; j < 8; ++j) v[j] = f2bs(src[j]);
    *reinterpret_cast<sh8*>(&WgL[i * 8]) = v;
  }
  for (int i = tid; i < 16 * 64; i += 512) {        // Mk: [ks][lane]
    const int ks = i >> 6, l2 = i & 63;
    const int col = l2 & 15, kg = l2 >> 4;
    const int k0 = ks * 32 + kg * 8;
    const int mr = 16 * ct + col;
    sh8 v;
    #pragma unroll
    for (int j = 0; j < 8; ++j)
      v[j] = (mr < MEM_) ? f2bs(Mkd[(size_t)mr * H_ + k0 + j]) : (short)0;
    *reinterpret_cast<sh8*>(&MkL[i * 8]) = v;
  }
  for (int i = tid; i < 16 * 2 * 64; i += 512) {    // Mf: [ks][ct2][lane]
    const int ks = i >> 7, r2 = i & 127, ct2 = r2 >> 6, l2 = r2 & 63;
    const int col = l2 & 15, kg = l2 >> 4;
    const int gc = (col & 3) * H_ + 8 * w + 4 * ct2 + (col >> 2);
    const int m0 = ks * 32 + kg * 8;
    sh8 v;
    #pragma unroll
    for (int j = 0; j < 8; ++j)
      v[j] = (m0 + j < MEM_) ? f2bs(Mfd[(size_t)(m0 + j) * G4_ + gc]) : (short)0;
    *reinterpret_cast<sh8*>(&MfL[i * 8]) = v;
  }
  if (tid < B_) LvL[tid] = p.len[tid];

  // per-lane cell mapping
  const int cc  = lane & 15;
  const int q   = cc & 3;
  const int uu  = cc >> 2;
  const int kg8 = (lane >> 4) * 8;
  const int arow = lane & 15;
  float biasl[2];
  #pragma unroll
  for (int ct2 = 0; ct2 < 2; ++ct2) {
    const int gc = q * H_ + 8 * w + 4 * ct2 + uu;
    biasl[ct2] = bihd[gc] + bhhd[gc];
  }

  float creg[2][4] = {{0.f,0.f,0.f,0.f},{0.f,0.f,0.f,0.f}};
  __syncthreads();                     // LDS + LvL ready (only barrier in kernel)

  const int mylen = LvL[16 * wv + arow];   // for bwd producer masking

  // gate x-half MFMA (xbf / x only; no cross-WG dependence)
  auto xhalf = [&](int t, f32x4* acc) {
    if (p.xbf) {
      const short* xb = p.xbf + ((size_t)(16 * wv + arow) * T_ + t) * E_ + kg8;
      for (int ks = 0; ks < 16; ++ks) {
        sh8 af = *reinterpret_cast<const sh8*>(xb + ks * 32);
        acc[0] = __builtin_amdgcn_mfma_f32_16x16x32_bf16(
            af, *reinterpret_cast<const sh8*>(&WgL[((ks * 2 + 0) * 64 + lane) * 8]), acc[0], 0, 0, 0);
        acc[1] = __builtin_amdgcn_mfma_f32_16x16x32_bf16(
            af, *reinterpret_cast<const sh8*>(&WgL[((ks * 2 + 1) * 64 + lane) * 8]), acc[1], 0, 0, 0);
      }
    } else {
      const float* xp0 = p.x + ((size_t)(16 * wv + arow) * T_ + t) * E_ + kg8;
      for (int ks = 0; ks < 16; ++ks) {
        f32x4 v0 = *reinterpret_cast<const f32x4*>(xp0 + ks * 32);
        f32x4 v1 = *reinterpret_cast<const f32x4*>(xp0 + ks * 32 + 4);
        sh8 af;
        #pragma unroll
        for (int j = 0; j < 4; ++j) { af[j] = f2bs(v0[j]); af[4 + j] = f2bs(v1[j]); }
        acc[0] = __builtin_amdgcn_mfma_f32_16x16x32_bf16(
            af, *reinterpret_cast<const sh8*>(&WgL[((ks * 2 + 0) * 64 + lane) * 8]), acc[0], 0, 0, 0);
        acc[1] = __builtin_amdgcn_mfma_f32_16x16x32_bf16(
            af, *reinterpret_cast<const sh8*>(&WgL[((ks * 2 + 1) * 64 + lane) * 8]), acc[1], 0, 0, 0);
      }
    }
  };

  f32x4 accX[2] = {(f32x4){0,0,0,0}, (f32x4){0,0,0,0}};
  xhalf(dir ? T_ - 1 : 0, accX);                    // prologue: x-half for step 0

  for (int s = 0; s < T_; ++s) {
    const int t   = dir ? (T_ - 1 - s) : s;
    const int cur = s & 1, prv = cur ^ 1;
    const short* __restrict__ hb_prev = p.hbf + ((size_t)(prv * 2 + dir)) * B_ * H_;
    short*       __restrict__ hb_cur  = p.hbf + ((size_t)(cur * 2 + dir)) * B_ * H_;

    const short* hrow = hb_prev + (size_t)(16 * wv + arow) * H_ + kg8;

    f32x4 accG[2] = { accX[0], accX[1] };           // x-half (prefetched)

    // ===== A: wait h-flags of step s-1 (dense row), then issue waited load
    if (s > 0) spin_h(hflW, (unsigned)s, lane);
    __builtin_amdgcn_sched_barrier(0);
    F16 fH;
    gld16(fH, hrow);

    // ===== B: balanced producers: attn logits -> exp -> aB + flag (own rows).
    // bwd memory read uses hm(s-1) = h(s-1) * ((t+1) < len) — locally masked
    // fH rows (r13 identity; at s=0 mask=0 => logits 0 => exp=1 as reference).
    if (prod) {
      f32x4 accA = (f32x4){0, 0, 0, 0};
      const sh8 z8 = (sh8){0,0,0,0,0,0,0,0};
      const bool keep = !dir || ((t + 1) < mylen);
      for (int ks = 0; ks < 16; ++ks) {
        sh8 af = keep ? fH.v[ks] : z8;
        accA = __builtin_amdgcn_mfma_f32_16x16x32_bf16(
            af, *reinterpret_cast<const sh8*>(&MkL[(ks * 64 + lane) * 8]), accA, 0, 0, 0);
      }
      const int m = 16 * ct + arow;
      unsigned d[4];
      #pragma unroll
      for (int r = 0; r < 4; ++r) {
        float e = (m < MEM_) ? __expf(accA[r]) : 0.f;
        d[r] = (unsigned)(unsigned short)f2bs(e);
      }
      st4s(aBd + (size_t)(16 * wv + 4 * (lane >> 4)) * 512 + m, d[0], d[1], d[2], d[3]);
      fset(&aflW[ct], (unsigned)(s + 1), lane);
    }

    // ===== C: gate h-half MFMA (fH only) — overlaps producers' store/flag time
    for (int ks = 0; ks < 16; ++ks) {
      accG[0] = __builtin_amdgcn_mfma_f32_16x16x32_bf16(
          fH.v[ks], *reinterpret_cast<const sh8*>(&WgL[(((16 + ks) * 2 + 0) * 64 + lane) * 8]), accG[0], 0, 0, 0);
      accG[1] = __builtin_amdgcn_mfma_f32_16x16x32_bf16(
          fH.v[ks], *reinterpret_cast<const sh8*>(&WgL[(((16 + ks) * 2 + 1) * 64 + lane) * 8]), accG[1], 0, 0, 0);
    }

    // ===== F: next step's x-half prefetch fills the aB wait window
    accX[0] = (f32x4){0,0,0,0}; accX[1] = (f32x4){0,0,0,0};
    if (s + 1 < T_) xhalf(dir ? (T_ - 2 - s) : (s + 1), accX);

    // ===== D: wait aB flags (dense), waited fC load, ctx MFMA + softmax denom
    f32x4 accC[2] = {(f32x4){0,0,0,0}, (f32x4){0,0,0,0}};
    float inv4[4] = {0.f, 0.f, 0.f, 0.f};
    if (s > 0) {
      spin_a(aflW, (unsigned)(s + 1), lane);
      __builtin_amdgcn_sched_barrier(0);
      F16 fC;
      gld16(fC, aBd + (size_t)(16 * wv + arow) * 512 + kg8);
      float rs = 0.f;
      for (int ks = 0; ks < 16; ++ks) {
        accC[0] = __builtin_amdgcn_mfma_f32_16x16x32_bf16(
            fC.v[ks], *reinterpret_cast<const sh8*>(&MfL[((ks * 2 + 0) * 64 + lane) * 8]), accC[0], 0, 0, 0);
        accC[1] = __builtin_amdgcn_mfma_f32_16x16x32_bf16(
            fC.v[ks], *reinterpret_cast<const sh8*>(&MfL[((ks * 2 + 1) * 64 + lane) * 8]), accC[1], 0, 0, 0);
        #pragma unroll
        for (int j = 0; j < 8; ++j) rs += bs2f(fC.v[ks][j]);
      }
      rs += __shfl_xor(rs, 16);
      rs += __shfl_xor(rs, 32);                     // lane holds rowsum(16wv+arow)
      #pragma unroll
      for (int r = 0; r < 4; ++r)
        inv4[r] = 1.f / __shfl(rs, 4 * (lane >> 4) + r);
    }

    // ===== E: cell update + h stores + h-flag
    unsigned hsd[8]; float hvv[2][4];
    #pragma unroll
    for (int ct2 = 0; ct2 < 2; ++ct2) {
      float g4[4];
      #pragma unroll
      for (int r = 0; r < 4; ++r) {
        float v = accG[ct2][r] + biasl[ct2];
        if (s > 0) v += accC[ct2][r] * inv4[r];
        g4[r] = v;
      }
      #pragma unroll
      for (int r = 0; r < 4; ++r) {
        const float x1 = __shfl_xor(g4[r], 1);
        const float x2 = __shfl_xor(g4[r], 2);
        const float x3 = __shfl_xor(g4[r], 3);
        const float iv = (q==0)?g4[r]:(q==1)?x1:(q==2)?x2:x3;
        const float fv = (q==0)?x1:(q==1)?g4[r]:(q==2)?x3:x2;
        const float gv = (q==0)?x2:(q==1)?x3:(q==2)?g4[r]:x1;
        const float ov = (q==0)?x3:(q==1)?x2:(q==2)?x1:g4[r];
        float cv = creg[ct2][r];
        cv = sigm_(fv) * cv + sigm_(iv) * tanh_(gv);
        const float hv = sigm_(ov) * tanh_(cv);
        creg[ct2][r] = cv;
        hvv[ct2][r] = hv;
        hsd[ct2 * 4 + r] = (unsigned)(unsigned short)f2bs(hv);
      }
    }
    if (q == 0) {
      const int b0 = 16 * wv + 4 * (lane >> 4);
      const int unit0 = 8 * w + uu;
      unsigned hord[8] = {hsd[0],hsd[1],hsd[2],hsd[3],hsd[4],hsd[5],hsd[6],hsd[7]};
      st8s(hb_cur + (size_t)b0 * H_ + unit0, hord);
      #pragma unroll
      for (int ct2 = 0; ct2 < 2; ++ct2) {
        #pragma unroll
        for (int r = 0; r < 4; ++r) {
          const int b = b0 + r;
          const int unit = unit0 + 4 * ct2;
          if (dir == 0) {
            if (t == LvL[b] - 1) p.out[b * (2 * H_) + 2 * unit] = hvv[ct2][r];
          } else {
            if (s == T_ - 1) p.out[b * (2 * H_) + 2 * unit + 1] = hvv[ct2][r];
          }
        }
      }
    }
    asm volatile("s_waitcnt vmcnt(0)" ::: "memory");   // drain h stores
    fset(&hflW[w], (unsigned)(s + 1), lane);
  }
}

extern "C" void kernel_launch(void* const* d_in, const int* in_sizes, int n_in,
                              void* d_out, int out_size, void* d_ws, size_t ws_size,
                              hipStream_t stream) {
  (void)in_sizes; (void)n_in; (void)out_size;

  ScanParams p;
  p.x    = (const float*)d_in[0];
  p.len  = (const int*)  d_in[1];
  p.Wih0 = (const float*)d_in[2];
  p.Whh0 = (const float*)d_in[3];
  p.bih0 = (const float*)d_in[4];
  p.bhh0 = (const float*)d_in[5];
  p.Wih1 = (const float*)d_in[6];
  p.Whh1 = (const float*)d_in[7];
  p.bih1 = (const float*)d_in[8];
  p.bhh1 = (const float*)d_in[9];
  p.Mk0  = (const float*)d_in[10];
  const float* MvF = (const float*)d_in[11];
  p.Mk1  = (const float*)d_in[12];
  const float* MvB = (const float*)d_in[13];

  char* ws = (char*)d_ws;
  size_t off = 0;
  auto alloc = [&](size_t bytes) -> void* {
    void* ptr = ws + off; off += (bytes + 255) & ~(size_t)255; return ptr;
  };
  float*    Mf   = (float*)   alloc((size_t)2 * MEM_ * G4_ * 4);      // 8.19 MB
  short*    hbf  = (short*)   alloc((size_t)2 * 2 * B_ * H_ * 2);     // 512 KB (2 par)
  short*    aB   = (short*)   alloc((size_t)2 * B_ * 512 * 2);        // 256 KB
  unsigned* bar  = (unsigned*)alloc((size_t)1536 * sizeof(unsigned)); // 6 KB dense flags
  size_t xbf_off = off;
  short*    xbf  = (short*)   alloc((size_t)B_ * T_ * E_ * 2);        // 67 MB
  const bool useXbf = (ws_size >= xbf_off + (size_t)B_ * T_ * E_ * 2);

  p.Mf = Mf; p.hbf = hbf; p.aB = aB; p.bar = bar;
  p.xbf = useXbf ? xbf : nullptr;
  p.out = (float*)d_out;

  // zero bf16 recurrent state and flag state, each call
  hipMemsetAsync(hbf, 0, (size_t)2 * 2 * B_ * H_ * 2, stream);
  hipMemsetAsync(bar, 0, (size_t)1536 * sizeof(unsigned), stream);

  if (useXbf) {
    const size_t n8 = (size_t)B_ * T_ * E_ / 8;
    xcvt_kernel<<<dim3((unsigned)(n8 / 256)), dim3(256), 0, stream>>>(p.x, xbf);
  }
  mfused_kernel<<<dim3(256), dim3(256), 0, stream>>>(
      (const float*)d_in[2], (const float*)d_in[6], MvF, MvB, Mf);

  void* args[] = { &p };
  hipLaunchCooperativeKernel((const void*)scan_kernel, dim3(128), dim3(512),
                             args, 0, stream);
}